// Round 8
// baseline (75.621 us; speedup 1.0000x reference)
//
#include <hip/hip_runtime.h>
#include <hip/hip_bf16.h>
#include <math.h>

// Problem constants (B=64, T=512, D=1024 from reference setup)
constexpr int   Bc       = 64;
constexpr int   Tc       = 512;
constexpr int   Dc       = 1024;
constexpr int   NMc      = 5;
constexpr int   TvC      = Tc - NMc - 1;   // 506
constexpr float TEMP_INV = 10.0f;

using bf16x8 = __attribute__((ext_vector_type(8))) short;
using f32x4  = __attribute__((ext_vector_type(4))) float;

__device__ inline short f2bf(float f) {   // round-to-nearest-even
    unsigned u = __float_as_uint(f);
    unsigned r = (u + 0x7fffu + ((u >> 16) & 1u)) >> 16;
    return (short)r;
}
__device__ inline float wave_reduce_sum(float v) {
#pragma unroll
    for (int off = 32; off; off >>= 1) v += __shfl_xor(v, off);
    return v;
}

#define GLOAD16(gp, lp)                                                        \
    __builtin_amdgcn_global_load_lds(                                          \
        (const __attribute__((address_space(1))) void*)(gp),                   \
        (__attribute__((address_space(3))) void*)(lp), 16, 0, 0)

// ---------------------------------------------------------------------------
// Kernel 1: normalize rows -> bf16 feats. Wave-per-row, no LDS, no barriers.
// Also zeroes the output accumulator (block 0): stream-ordered before combine.
__global__ __launch_bounds__(256) void tcl_prep(const float* __restrict__ h,
                                                short* __restrict__ fb,
                                                float* __restrict__ out) {
    if (blockIdx.x == 0 && threadIdx.x == 0) *out = 0.f;
    const int row  = blockIdx.x * 4 + (threadIdx.x >> 6);
    const int lane = threadIdx.x & 63;
    const float4* h4 = reinterpret_cast<const float4*>(h) + (size_t)row * 256 + lane;
    float4 v[4];
    float ss = 0.f;
#pragma unroll
    for (int i = 0; i < 4; ++i) {
        v[i] = h4[i * 64];
        ss += v[i].x*v[i].x + v[i].y*v[i].y + v[i].z*v[i].z + v[i].w*v[i].w;
    }
    ss = wave_reduce_sum(ss);                       // all lanes hold total
    const float inv = 1.0f / fmaxf(sqrtf(ss), 1e-12f);
    short4* o4 = reinterpret_cast<short4*>(fb + (size_t)row * Dc) + lane;
#pragma unroll
    for (int i = 0; i < 4; ++i) {
        short4 o;
        o.x = f2bf(v[i].x * inv); o.y = f2bf(v[i].y * inv);
        o.z = f2bf(v[i].z * inv); o.w = f2bf(v[i].w * inv);
        o4[i * 64] = o;
    }
}

// ---------------------------------------------------------------------------
// Kernel 2: MFMA negative-score pass + fused positive extraction.
// 64(t) x 128(s) tile jobs, 20 per batch -> 1280 blocks (5/CU, uniform cost).
// BK=64, DOUBLE-BUFFERED LDS (2-phase): stage tile k+1 before compute of tile
// k; ONE __syncthreads per step (its implicit vmcnt(0) drain is the only
// wait) -> stage latency hides under 16 MFMA + 6 ds_read of the current tile.
// 4 waves (2x2); wave = 32x64 C as 2x4 frags of 16x16x32 bf16.
// global_load_lds width=16, linear LDS dest + XOR-swizzled GLOBAL source;
// ds_read offsets XOR-matched (both-sides-or-neither rule).
// Fixed-ref logsumexp: scores are 10*cos in [-10,10] => S += exp(sc-10).
// S_part[b][sj][t]: write-once. Positives fused: diagonal jobs harvest
// in-segment pairs (pos_d); x-jobs (ti==2sj-1) harvest boundary pairs (pos_x).
__device__ __constant__ unsigned char JOB_TI[20] =
    {0,1, 0,1,2,3, 0,1,2,3,4,5, 0,1,2,3,4,5,6,7};
__device__ __constant__ unsigned char JOB_SJ[20] =
    {0,0, 1,1,1,1, 2,2,2,2,2,2, 3,3,3,3,3,3,3,3};

__global__ __launch_bounds__(256) void tcl_scores(const short* __restrict__ fb,
                                                  float* __restrict__ S_part,
                                                  float* __restrict__ pos_d,
                                                  float* __restrict__ pos_x) {
    // XCD-chunked swizzle: p%8 = XCD chunk; each batch's 20 jobs share an XCD.
    const int p  = blockIdx.x;
    const int b  = (p & 7) * 8 + ((p >> 3) / 20);
    const int j  = (p >> 3) % 20;
    const int ti = (int)JOB_TI[j];
    const int sj = (int)JOB_SJ[j];
    const int t0 = ti * 64;
    const int s0 = sj * 128;
    const bool is_diag = (ti == 2 * sj) || (ti == 2 * sj + 1);
    const bool is_x    = (ti == 2 * sj - 1);

    const short* f = fb + (size_t)b * Tc * Dc;
    const int lane = threadIdx.x & 63;
    const int wid  = threadIdx.x >> 6;
    const int wr   = wid >> 1, wc = wid & 1;

    __shared__ short Als[2 * 64 * 64];    // 2 x 8 KB (buf stride 4096 shorts)
    __shared__ short Bls[2 * 128 * 64];   // 2 x 16 KB (buf stride 8192 shorts)

    // ---- staging addresses (per-lane global, linear LDS dest) ----
    // Each 1KB gload_lds instr covers 8 rows x 128 B. lane l -> row sub=l>>3,
    // col chunk c8=l&7, source chunk XOR-permuted: csw = (c8 ^ sub) * 8 shorts.
    const int sub = lane >> 3;
    const int c8  = lane & 7;
    const int csw = (c8 ^ sub) << 3;
    const short* gA[2]; const short* gB[4];
    int lAo[2]; int lBo[4];
#pragma unroll
    for (int i = 0; i < 2; ++i) {
        const int ri = wid * 2 + i;               // 0..7
        gA[i] = f + (size_t)(t0 + ri * 8 + sub) * Dc + csw;
        lAo[i] = ri * 512;                        // 1024 B regions
    }
#pragma unroll
    for (int i = 0; i < 4; ++i) {
        const int ri = wid * 4 + i;               // 0..15
        gB[i] = f + (size_t)(s0 + ri * 8 + sub) * Dc + csw;
        lBo[i] = ri * 512;
    }

#define STAGE(BUF)                                                             \
    do {                                                                       \
        _Pragma("unroll")                                                      \
        for (int i = 0; i < 2; ++i) {                                          \
            GLOAD16(gA[i], Als + (BUF) * 4096 + lAo[i]);                       \
            gA[i] += 64;                                                       \
        }                                                                      \
        _Pragma("unroll")                                                      \
        for (int i = 0; i < 4; ++i) {                                          \
            GLOAD16(gB[i], Bls + (BUF) * 8192 + lBo[i]);                       \
            gB[i] += 64;                                                       \
        }                                                                      \
    } while (0)

    // ---- fragment read offsets (shorts), swizzled to match ----
    const int r16 = lane & 15, kg = lane >> 4;
    int aoff[2][2], boff[4][2];
#pragma unroll
    for (int ks = 0; ks < 2; ++ks) {
        const int cb = (ks * 64 + kg * 16) ^ ((r16 & 7) << 4);  // bytes
#pragma unroll
        for (int q = 0; q < 2; ++q)
            aoff[q][ks] = (wr * 32 + q * 16 + r16) * 64 + (cb >> 1);
#pragma unroll
        for (int q = 0; q < 4; ++q)
            boff[q][ks] = (wc * 64 + q * 16 + r16) * 64 + (cb >> 1);
    }

    f32x4 acc[2][4];
#pragma unroll
    for (int fa = 0; fa < 2; ++fa)
#pragma unroll
        for (int fbj = 0; fbj < 4; ++fbj) acc[fa][fbj] = f32x4{0.f, 0.f, 0.f, 0.f};

#define COMPUTE(BUF)                                                           \
    do {                                                                       \
        bf16x8 av[2][2], bv[4][2];                                             \
        _Pragma("unroll")                                                      \
        for (int ks = 0; ks < 2; ++ks) {                                       \
            _Pragma("unroll")                                                  \
            for (int q = 0; q < 2; ++q)                                        \
                av[q][ks] = *(const bf16x8*)(Als + (BUF) * 4096 + aoff[q][ks]);\
            _Pragma("unroll")                                                  \
            for (int q = 0; q < 4; ++q)                                        \
                bv[q][ks] = *(const bf16x8*)(Bls + (BUF) * 8192 + boff[q][ks]);\
        }                                                                      \
        _Pragma("unroll")                                                      \
        for (int fa = 0; fa < 2; ++fa)                                         \
            _Pragma("unroll")                                                  \
            for (int fbj = 0; fbj < 4; ++fbj)                                  \
                _Pragma("unroll")                                              \
                for (int ks = 0; ks < 2; ++ks)                                 \
                    acc[fa][fbj] = __builtin_amdgcn_mfma_f32_16x16x32_bf16(    \
                        av[fa][ks], bv[fbj][ks], acc[fa][fbj], 0, 0, 0);       \
    } while (0)

    // ---- 2-phase K loop: 16 steps of BK=64, manual 2x unroll (static bufs) --
    STAGE(0);                    // tile 0 -> buf 0
    __syncthreads();             // drain (prologue only)
    for (int kt = 0; kt < 16; kt += 2) {
        STAGE(1);                // tile kt+1 -> buf 1 (overlaps compute below)
        COMPUTE(0);              // tile kt
        __syncthreads();         // implicit vmcnt(0): buf1 ready; buf0 free
        if (kt < 14) STAGE(0);   // tile kt+2 -> buf 0
        COMPUTE(1);              // tile kt+1
        __syncthreads();
    }
#undef STAGE
#undef COMPUTE

    // ---- epilogue: exp-sum (masked) + positive row-side harvest ----
    __shared__ float S_sh[2][64];
    __shared__ float P_sh[2][64];
#pragma unroll
    for (int fa = 0; fa < 2; ++fa) {
#pragma unroll
        for (int r = 0; r < 4; ++r) {
            const int trow = t0 + wr * 32 + fa * 16 + kg * 4 + r;
            float v = 0.f, pv = 0.f;
#pragma unroll
            for (int fbj = 0; fbj < 4; ++fbj) {
                const int col = s0 + wc * 64 + fbj * 16 + r16;
                const float sc = acc[fa][fbj][r] * TEMP_INV;
                v += (col >= trow + NMc) ? __expf(sc - 10.f) : 0.f;
                const int dd = col - trow;
                pv += (dd * dd == 1 || dd * dd == 4) ? sc : 0.f;
            }
#pragma unroll
            for (int off = 1; off < 16; off <<= 1) {
                v  += __shfl_xor(v, off);
                pv += __shfl_xor(pv, off);
            }
            if (r16 == 0) {
                const int rl = wr * 32 + fa * 16 + kg * 4 + r;
                S_sh[wc][rl] = v;
                P_sh[wc][rl] = pv;
            }
        }
    }

    // ---- col-side positive harvest (x-jobs only) ----
    // Pairs (u, v): u = t0+62/63 (rows), v = s0/s0+1 (cols); value = sc(u,v)
    // feeds pos[v]. Rows 62/63 live in wave wr=1; cols s0/s0+1 in wc=0, fbj=0.
    if (is_x && wr == 1 && wc == 0) {
        float cv = 0.f;
        const int c = s0 + r16;
#pragma unroll
        for (int fa = 0; fa < 2; ++fa)
#pragma unroll
            for (int r = 0; r < 4; ++r) {
                const int trow = t0 + 32 + fa * 16 + kg * 4 + r;
                const int dd = c - trow;
                cv += (dd == 1 || dd == 2) ? acc[fa][0][r] * TEMP_INV : 0.f;
            }
        cv += __shfl_xor(cv, 16);
        cv += __shfl_xor(cv, 32);
        if (kg == 0 && r16 < 2) pos_x[(size_t)b * Tc + c] = cv;
    }

    __syncthreads();
    if (threadIdx.x < 64) {
        const int t = t0 + threadIdx.x;
        S_part[((size_t)b * 4 + sj) * Tc + t] = S_sh[0][threadIdx.x] + S_sh[1][threadIdx.x];
        const float pr = P_sh[0][threadIdx.x] + P_sh[1][threadIdx.x];
        if (is_diag)
            pos_d[(size_t)b * Tc + t] = pr;
        if (is_x && threadIdx.x >= 62)             // rows t0+62, t0+63
            pos_x[(size_t)b * Tc + t] = pr;
    }
}

// ---------------------------------------------------------------------------
// Kernel 3: trivial combine. One block per batch; reads S_part slices + pos
// tables, closes the logsumexp, block-reduce, ONE atomicAdd per block.
__global__ __launch_bounds__(256) void tcl_combine(const float* __restrict__ S_part,
                                                   const float* __restrict__ pos_d,
                                                   const float* __restrict__ pos_x,
                                                   float* __restrict__ out, float scale) {
    const int b = blockIdx.x;
    float lsum = 0.f;
    for (int t = threadIdx.x; t < TvC; t += 256) {
        const int ti = t >> 7, tl = t & 127;
        float S = 0.f;
        for (int sj = ti; sj < 4; ++sj) S += S_part[((size_t)b * 4 + sj) * Tc + t];
        float praw = pos_d[(size_t)b * Tc + t];
        if ((tl >= 126 && ti < 3) || (tl <= 1 && ti > 0))
            praw += pos_x[(size_t)b * Tc + t];
        const float cnt = (t == 0) ? 2.f : (t == 1) ? 3.f : 4.f;
        const float pos = praw / cnt;
        lsum += __logf(__expf(pos - 10.f) + S) + 10.f - pos;
    }
    lsum = wave_reduce_sum(lsum);
    __shared__ float wls[4];
    const int lane = threadIdx.x & 63, wid = threadIdx.x >> 6;
    if (lane == 0) wls[wid] = lsum;
    __syncthreads();
    if (threadIdx.x == 0)
        atomicAdd(out, (wls[0] + wls[1] + wls[2] + wls[3]) * scale);
}

// ---------------------------------------------------------------------------
extern "C" void kernel_launch(void* const* d_in, const int* in_sizes, int n_in,
                              void* d_out, int out_size, void* d_ws, size_t ws_size,
                              hipStream_t stream) {
    const float* h = (const float*)d_in[0];
    float* out = (float*)d_out;

    const size_t feats_bytes = (size_t)Bc * Tc * Dc * sizeof(short);   // 64 MiB
    const size_t spart_bytes = (size_t)Bc * 4 * Tc * sizeof(float);    // 512 KiB
    const size_t posd_bytes  = (size_t)Bc * Tc * sizeof(float);        // 128 KiB
    const float  scale       = 1.0f / (float)(Bc * TvC);

    short* fb     = (short*)d_ws;
    float* S_part = (float*)((char*)d_ws + feats_bytes);
    float* pos_d  = (float*)((char*)d_ws + feats_bytes + spart_bytes);
    float* pos_x  = (float*)((char*)d_ws + feats_bytes + spart_bytes + posd_bytes);

    tcl_prep<<<Bc * Tc / 4, 256, 0, stream>>>(h, fb, out);
    tcl_scores<<<Bc * 20, 256, 0, stream>>>(fb, S_part, pos_d, pos_x);
    tcl_combine<<<Bc, 256, 0, stream>>>(S_part, pos_d, pos_x, out, scale);
    (void)ws_size; (void)in_sizes; (void)n_in; (void)out_size;
}

// Round 9
// 75.062 us; speedup vs baseline: 1.0074x; 1.0074x over previous
//
#include <hip/hip_runtime.h>
#include <hip/hip_bf16.h>
#include <math.h>

// Problem constants (B=64, T=512, D=1024 from reference setup)
constexpr int   Bc       = 64;
constexpr int   Tc       = 512;
constexpr int   Dc       = 1024;
constexpr int   NMc      = 5;
constexpr int   TvC      = Tc - NMc - 1;   // 506
constexpr float TEMP_INV = 10.0f;

using bf16x8 = __attribute__((ext_vector_type(8))) short;
using f32x4  = __attribute__((ext_vector_type(4))) float;

__device__ inline short f2bf(float f) {   // round-to-nearest-even
    unsigned u = __float_as_uint(f);
    unsigned r = (u + 0x7fffu + ((u >> 16) & 1u)) >> 16;
    return (short)r;
}
__device__ inline float wave_reduce_sum(float v) {
#pragma unroll
    for (int off = 32; off; off >>= 1) v += __shfl_xor(v, off);
    return v;
}

#define GLOAD16(gp, lp)                                                        \
    __builtin_amdgcn_global_load_lds(                                          \
        (const __attribute__((address_space(1))) void*)(gp),                   \
        (__attribute__((address_space(3))) void*)(lp), 16, 0, 0)

// counted-vmcnt sync primitives (T4): never drain vmcnt to 0 in steady state
#define WAITV3() asm volatile("s_waitcnt vmcnt(3)" ::: "memory")
#define WAITV0() asm volatile("s_waitcnt vmcnt(0)" ::: "memory")
#define SBAR()   asm volatile("s_barrier" ::: "memory")
#define LBAR()   asm volatile("s_waitcnt lgkmcnt(0)\n\ts_barrier" ::: "memory")

// ---------------------------------------------------------------------------
// Kernel 1: normalize rows -> bf16 feats. Wave-per-row, no LDS, no barriers.
// Also zeroes the output accumulator (block 0): stream-ordered before combine.
__global__ __launch_bounds__(256) void tcl_prep(const float* __restrict__ h,
                                                short* __restrict__ fb,
                                                float* __restrict__ out) {
    if (blockIdx.x == 0 && threadIdx.x == 0) *out = 0.f;
    const int row  = blockIdx.x * 4 + (threadIdx.x >> 6);
    const int lane = threadIdx.x & 63;
    const float4* h4 = reinterpret_cast<const float4*>(h) + (size_t)row * 256 + lane;
    float4 v[4];
    float ss = 0.f;
#pragma unroll
    for (int i = 0; i < 4; ++i) {
        v[i] = h4[i * 64];
        ss += v[i].x*v[i].x + v[i].y*v[i].y + v[i].z*v[i].z + v[i].w*v[i].w;
    }
    ss = wave_reduce_sum(ss);                       // all lanes hold total
    const float inv = 1.0f / fmaxf(sqrtf(ss), 1e-12f);
    short4* o4 = reinterpret_cast<short4*>(fb + (size_t)row * Dc) + lane;
#pragma unroll
    for (int i = 0; i < 4; ++i) {
        short4 o;
        o.x = f2bf(v[i].x * inv); o.y = f2bf(v[i].y * inv);
        o.z = f2bf(v[i].z * inv); o.w = f2bf(v[i].w * inv);
        o4[i * 64] = o;
    }
}

// ---------------------------------------------------------------------------
// Kernel 2: MFMA negative-score pass + fused positive extraction.
// 64(t) x 128(s) tile jobs, 20/batch -> 1280 blocks (5/CU). BK=32,
// DOUBLE-BUFFERED LDS at 24 KB total (same occupancy as single-buffer BK=64:
// 6 blocks/CU) with COUNTED-vmcnt pipeline: STAGE(next) -> vmcnt(3) [cur's 3
// loads done, next's 3 stay in flight] -> s_barrier -> ds_read+MFMA(cur) ->
// lgkmcnt(0)+s_barrier. No vmcnt(0) drain in steady state (T4/AITER pattern).
// LDS layout: rows of 128 B holding TWO 64-B K-chunks (global rows r, r+HALF)
// so the proven XOR swizzle (slot ^= lrow&7, measured 0 conflicts) is kept;
// global_load_lds writes linearly, source pre-swizzled (both-sides rule).
// Fixed-ref logsumexp: scores are 10*cos in [-10,10] => S += exp(sc-10).
// S_part[b][sj][t] write-once; positives fused (pos_d diag, pos_x boundary).
__device__ __constant__ unsigned char JOB_TI[20] =
    {0,1, 0,1,2,3, 0,1,2,3,4,5, 0,1,2,3,4,5,6,7};
__device__ __constant__ unsigned char JOB_SJ[20] =
    {0,0, 1,1,1,1, 2,2,2,2,2,2, 3,3,3,3,3,3,3,3};

__global__ __launch_bounds__(256) void tcl_scores(const short* __restrict__ fb,
                                                  float* __restrict__ S_part,
                                                  float* __restrict__ pos_d,
                                                  float* __restrict__ pos_x) {
    // XCD-chunked swizzle: p%8 = XCD chunk; each batch's 20 jobs share an XCD.
    const int p  = blockIdx.x;
    const int b  = (p & 7) * 8 + ((p >> 3) / 20);
    const int j  = (p >> 3) % 20;
    const int ti = (int)JOB_TI[j];
    const int sj = (int)JOB_SJ[j];
    const int t0 = ti * 64;
    const int s0 = sj * 128;
    const bool is_diag = (ti == 2 * sj) || (ti == 2 * sj + 1);
    const bool is_x    = (ti == 2 * sj - 1);

    const short* f = fb + (size_t)b * Tc * Dc;
    const int lane = threadIdx.x & 63;
    const int wid  = threadIdx.x >> 6;
    const int wr   = wid >> 1, wc = wid & 1;

    // A: 64 rows -> 32 LDS rows x 128 B (halves 0/32 side by side) = 4 KB/buf
    // B: 128 rows -> 64 LDS rows x 128 B (halves 0/64)             = 8 KB/buf
    __shared__ short Als[2 * 2048];
    __shared__ short Bls[2 * 4096];

    // ---- staging: per-lane pre-swizzled global source, linear LDS dest ----
    // Region = 1 KB = 8 LDS rows. lane l -> lrow_local sub=l>>3, slot c8=l&7.
    // Stored content slot' = c8 ^ sub; slot'<4 -> low-half row, byte (slot'&3)*16.
    const int sub = lane >> 3;
    const int c8  = lane & 7;
    const int sp  = c8 ^ sub;                     // source slot'
    const int spb = (sp & 3) * 8;                 // shorts within 64-B k-chunk

    // A: one region per wave (lrows 8*wid .. 8*wid+7)
    const short* gA = f + (size_t)(t0 + wid * 8 + sub + ((sp >= 4) ? 32 : 0)) * Dc + spb;
    const int lAo = wid * 512;                    // shorts (wave-uniform)
    // B: two regions per wave
    const short* gB[2];
    int lBo[2];
#pragma unroll
    for (int i = 0; i < 2; ++i) {
        const int ri = wid * 2 + i;               // 0..7
        gB[i] = f + (size_t)(s0 + ri * 8 + sub + ((sp >= 4) ? 64 : 0)) * Dc + spb;
        lBo[i] = ri * 512;
    }

#define STAGE(BUF)                                                             \
    do {                                                                       \
        GLOAD16(gA, Als + (BUF) * 2048 + lAo); gA += 32;                       \
        _Pragma("unroll")                                                      \
        for (int i = 0; i < 2; ++i) {                                          \
            GLOAD16(gB[i], Bls + (BUF) * 4096 + lBo[i]); gB[i] += 32;          \
        }                                                                      \
    } while (0)

    // ---- fragment read offsets (shorts), swizzle-matched ----
    const int r16 = lane & 15, kg = lane >> 4;
    int aoff[2], boff[4];
#pragma unroll
    for (int q = 0; q < 2; ++q)
        aoff[q] = (q * 16 + r16) * 64 + (((wr << 2) + kg) ^ (r16 & 7)) * 8;
#pragma unroll
    for (int q = 0; q < 4; ++q)
        boff[q] = (q * 16 + r16) * 64 + (((wc << 2) + kg) ^ (r16 & 7)) * 8;

    f32x4 acc[2][4];
#pragma unroll
    for (int fa = 0; fa < 2; ++fa)
#pragma unroll
        for (int fbj = 0; fbj < 4; ++fbj) acc[fa][fbj] = f32x4{0.f, 0.f, 0.f, 0.f};

#define COMPUTE(BUF)                                                           \
    do {                                                                       \
        bf16x8 av[2], bv[4];                                                   \
        _Pragma("unroll")                                                      \
        for (int q = 0; q < 2; ++q)                                            \
            av[q] = *(const bf16x8*)(Als + (BUF) * 2048 + aoff[q]);            \
        _Pragma("unroll")                                                      \
        for (int q = 0; q < 4; ++q)                                            \
            bv[q] = *(const bf16x8*)(Bls + (BUF) * 4096 + boff[q]);            \
        _Pragma("unroll")                                                      \
        for (int fa = 0; fa < 2; ++fa)                                         \
            _Pragma("unroll")                                                  \
            for (int fbj = 0; fbj < 4; ++fbj)                                  \
                acc[fa][fbj] = __builtin_amdgcn_mfma_f32_16x16x32_bf16(        \
                    av[fa], bv[fbj], acc[fa][fbj], 0, 0, 0);                   \
    } while (0)

    // ---- pipelined K loop: 32 steps of BK=32, counted vmcnt, 2 buffers ----
    STAGE(0);                                      // kt 0
    for (int pp = 0; pp < 15; ++pp) {
        STAGE(1); WAITV3(); SBAR(); COMPUTE(0); LBAR();   // compute 2pp, stage 2pp+1
        STAGE(0); WAITV3(); SBAR(); COMPUTE(1); LBAR();   // compute 2pp+1, stage 2pp+2
    }
    STAGE(1); WAITV3(); SBAR(); COMPUTE(0); LBAR();       // compute kt30, stage kt31
    WAITV0(); SBAR(); COMPUTE(1);                          // compute kt31
#undef STAGE
#undef COMPUTE

    // ---- epilogue: exp-sum (masked) + positive row-side harvest ----
    __shared__ float S_sh[2][64];
    __shared__ float P_sh[2][64];
#pragma unroll
    for (int fa = 0; fa < 2; ++fa) {
#pragma unroll
        for (int r = 0; r < 4; ++r) {
            const int trow = t0 + wr * 32 + fa * 16 + kg * 4 + r;
            float v = 0.f, pv = 0.f;
#pragma unroll
            for (int fbj = 0; fbj < 4; ++fbj) {
                const int col = s0 + wc * 64 + fbj * 16 + r16;
                const float sc = acc[fa][fbj][r] * TEMP_INV;
                v += (col >= trow + NMc) ? __expf(sc - 10.f) : 0.f;
                const int dd = col - trow;
                pv += (dd * dd == 1 || dd * dd == 4) ? sc : 0.f;
            }
#pragma unroll
            for (int off = 1; off < 16; off <<= 1) {
                v  += __shfl_xor(v, off);
                pv += __shfl_xor(pv, off);
            }
            if (r16 == 0) {
                const int rl = wr * 32 + fa * 16 + kg * 4 + r;
                S_sh[wc][rl] = v;
                P_sh[wc][rl] = pv;
            }
        }
    }

    // ---- col-side positive harvest (x-jobs only) ----
    // Pairs (u, v): u = t0+62/63 (rows), v = s0/s0+1 (cols); value = sc(u,v)
    // feeds pos[v]. Rows 62/63 live in wave wr=1; cols s0/s0+1 in wc=0, fbj=0.
    if (is_x && wr == 1 && wc == 0) {
        float cv = 0.f;
        const int c = s0 + r16;
#pragma unroll
        for (int fa = 0; fa < 2; ++fa)
#pragma unroll
            for (int r = 0; r < 4; ++r) {
                const int trow = t0 + 32 + fa * 16 + kg * 4 + r;
                const int dd = c - trow;
                cv += (dd == 1 || dd == 2) ? acc[fa][0][r] * TEMP_INV : 0.f;
            }
        cv += __shfl_xor(cv, 16);
        cv += __shfl_xor(cv, 32);
        if (kg == 0 && r16 < 2) pos_x[(size_t)b * Tc + c] = cv;
    }

    __syncthreads();
    if (threadIdx.x < 64) {
        const int t = t0 + threadIdx.x;
        S_part[((size_t)b * 4 + sj) * Tc + t] = S_sh[0][threadIdx.x] + S_sh[1][threadIdx.x];
        const float pr = P_sh[0][threadIdx.x] + P_sh[1][threadIdx.x];
        if (is_diag)
            pos_d[(size_t)b * Tc + t] = pr;
        if (is_x && threadIdx.x >= 62)             // rows t0+62, t0+63
            pos_x[(size_t)b * Tc + t] = pr;
    }
}

// ---------------------------------------------------------------------------
// Kernel 3: trivial combine. One block per batch; reads S_part slices + pos
// tables, closes the logsumexp, block-reduce, ONE atomicAdd per block.
__global__ __launch_bounds__(256) void tcl_combine(const float* __restrict__ S_part,
                                                   const float* __restrict__ pos_d,
                                                   const float* __restrict__ pos_x,
                                                   float* __restrict__ out, float scale) {
    const int b = blockIdx.x;
    float lsum = 0.f;
    for (int t = threadIdx.x; t < TvC; t += 256) {
        const int ti = t >> 7, tl = t & 127;
        float S = 0.f;
        for (int sj = ti; sj < 4; ++sj) S += S_part[((size_t)b * 4 + sj) * Tc + t];
        float praw = pos_d[(size_t)b * Tc + t];
        if ((tl >= 126 && ti < 3) || (tl <= 1 && ti > 0))
            praw += pos_x[(size_t)b * Tc + t];
        const float cnt = (t == 0) ? 2.f : (t == 1) ? 3.f : 4.f;
        const float pos = praw / cnt;
        lsum += __logf(__expf(pos - 10.f) + S) + 10.f - pos;
    }
    lsum = wave_reduce_sum(lsum);
    __shared__ float wls[4];
    const int lane = threadIdx.x & 63, wid = threadIdx.x >> 6;
    if (lane == 0) wls[wid] = lsum;
    __syncthreads();
    if (threadIdx.x == 0)
        atomicAdd(out, (wls[0] + wls[1] + wls[2] + wls[3]) * scale);
}

// ---------------------------------------------------------------------------
extern "C" void kernel_launch(void* const* d_in, const int* in_sizes, int n_in,
                              void* d_out, int out_size, void* d_ws, size_t ws_size,
                              hipStream_t stream) {
    const float* h = (const float*)d_in[0];
    float* out = (float*)d_out;

    const size_t feats_bytes = (size_t)Bc * Tc * Dc * sizeof(short);   // 64 MiB
    const size_t spart_bytes = (size_t)Bc * 4 * Tc * sizeof(float);    // 512 KiB
    const size_t posd_bytes  = (size_t)Bc * Tc * sizeof(float);        // 128 KiB
    const float  scale       = 1.0f / (float)(Bc * TvC);

    short* fb     = (short*)d_ws;
    float* S_part = (float*)((char*)d_ws + feats_bytes);
    float* pos_d  = (float*)((char*)d_ws + feats_bytes + spart_bytes);
    float* pos_x  = (float*)((char*)d_ws + feats_bytes + spart_bytes + posd_bytes);

    tcl_prep<<<Bc * Tc / 4, 256, 0, stream>>>(h, fb, out);
    tcl_scores<<<Bc * 20, 256, 0, stream>>>(fb, S_part, pos_d, pos_x);
    tcl_combine<<<Bc, 256, 0, stream>>>(S_part, pos_d, pos_x, out, scale);
    (void)ws_size; (void)in_sizes; (void)n_in; (void)out_size;
}